// Round 1
// baseline (1286.550 us; speedup 1.0000x reference)
//
#include <hip/hip_runtime.h>
#include <math.h>

#define Bb 16
#define Nn 4096
#define Hh 256
#define Pp 128
#define Lc 32
#define NCc (Nn / Lc)   // 128 chunks per batch
#define LP 36           // padded LDS chunk stride (floats)

__device__ __forceinline__ float gelu_f(float x) {
    return 0.5f * x * (1.f + erff(0.70710678118654752f * x));
}

// ---------------- K0a: transpose/interleave small matrices ----------------
__global__ void k0_transpose(const float* __restrict__ B_re, const float* __restrict__ B_im,
                             const float* __restrict__ E_re, const float* __restrict__ E_im,
                             const float* __restrict__ C_re, const float* __restrict__ C_im,
                             float* __restrict__ Bt2, float* __restrict__ Et2,
                             float* __restrict__ Ct2) {
    int idx = blockIdx.x * blockDim.x + threadIdx.x;  // over H*P
    if (idx >= Hh * Pp) return;
    int h = idx / Pp, p = idx % Pp;
    ((float2*)Bt2)[h * Pp + p] = make_float2(B_re[p * Hh + h], B_im[p * Hh + h]);
    ((float2*)Et2)[h * Pp + p] = make_float2(E_re[p * Hh + h], E_im[p * Hh + h]);
    ((float2*)Ct2)[p * Hh + h] = make_float2(C_re[h * Pp + p], C_im[h * Pp + p]);
}

// ---------------- K0b: M = 2*Re(C @ E)  [H,H], stored Mt[h2*H + h] ----------------
__global__ void k0_M(const float* __restrict__ C_re, const float* __restrict__ C_im,
                     const float* __restrict__ E_re, const float* __restrict__ E_im,
                     float* __restrict__ Mt) {
    int h2 = blockIdx.x;
    int h = threadIdx.x;
    float acc = 0.f;
    for (int p = 0; p < Pp; ++p)
        acc += C_re[h * Pp + p] * E_re[p * Hh + h2] - C_im[h * Pp + p] * E_im[p * Hh + h2];
    Mt[h2 * Hh + h] = 2.0f * acc;
}

// ---------------- K1: per-(b,chunk): LN(right[n-1]) -> Bu, imp; c; chunk-local scan agg ----
__global__ __launch_bounds__(512) void k1(
    const float* __restrict__ right, const float* __restrict__ mark,
    const float* __restrict__ dt, const float* __restrict__ llnr,
    const float* __restrict__ lim, const float* __restrict__ x0r,
    const float* __restrict__ x0i, const float* __restrict__ ln_g,
    const float* __restrict__ ln_b, const float* __restrict__ Bt2,
    const float* __restrict__ Et2, float* __restrict__ c_ws,
    float* __restrict__ xagg, float* __restrict__ Sdt) {
    __shared__ float u_t[Hh * LP];       // LN'd u_prev, transposed [h][r], 36 KB
    __shared__ float2 c_lds[Lc][Pp];     // 32 KB
    __shared__ float dt_s[Lc];

    const int bid = blockIdx.x;
    const int bi = bid / NCc, ch = bid % NCc;
    const int n0 = ch * Lc;
    const int t = threadIdx.x;
    const int lane = t & 63, wave = t >> 6;

    if (t < Lc) dt_s[t] = dt[(size_t)bi * Nn + n0 + t];

    // phase 1: LN stats + transposed staging of u_prev rows (row r <- right[n0+r-1])
    for (int rr = 0; rr < 4; ++rr) {
        const int r = wave * 4 + rr;
        const int nr = n0 + r - 1;
        if (nr < 0) {
            for (int j = 0; j < 4; ++j) u_t[(lane * 4 + j) * LP + r] = 0.f;
        } else {
            const float4 v = *reinterpret_cast<const float4*>(
                right + ((size_t)bi * Nn + nr) * Hh + lane * 4);
            float s = v.x + v.y + v.z + v.w;
            float q = v.x * v.x + v.y * v.y + v.z * v.z + v.w * v.w;
#pragma unroll
            for (int off = 32; off; off >>= 1) {
                s += __shfl_xor(s, off);
                q += __shfl_xor(q, off);
            }
            const float mu = s * (1.f / Hh);
            const float rstd = rsqrtf(q * (1.f / Hh) - mu * mu + 1e-5f);
            const float vv[4] = {v.x, v.y, v.z, v.w};
            for (int j = 0; j < 4; ++j) {
                const int h = lane * 4 + j;
                u_t[h * LP + r] = (vv[j] - mu) * rstd * ln_g[h] + ln_b[h];
            }
        }
    }
    __syncthreads();

    // phase 2: matmul — thread owns p = t&127, rows r0..r0+7
    const int p = t & (Pp - 1);
    const int r0 = (t >> 7) * 8;
    float bu_re[8] = {}, bu_im[8] = {}, imr[8] = {}, imi[8] = {};
    const float2* Bt = (const float2*)Bt2;
    const float2* Et = (const float2*)Et2;
    const size_t mbase = ((size_t)bi * Nn + n0 + r0) * Hh;
    for (int h = 0; h < Hh; ++h) {
        const float2 Bv = Bt[h * Pp + p];
        const float2 Ev = Et[h * Pp + p];
        const float* up = &u_t[h * LP + r0];
#pragma unroll
        for (int j = 0; j < 8; ++j) {
            const float u = up[j];
            const float m = mark[mbase + (size_t)j * Hh + h];
            bu_re[j] = fmaf(Bv.x, u, bu_re[j]);
            bu_im[j] = fmaf(Bv.y, u, bu_im[j]);
            imr[j] = fmaf(Ev.x, m, imr[j]);
            imi[j] = fmaf(Ev.y, m, imi[j]);
        }
    }
    const float lr = -expf(llnr[p]);
    const float li = lim[p];
    const float linv = 1.f / (lr * lr + li * li);
#pragma unroll
    for (int j = 0; j < 8; ++j) {
        const int r = r0 + j;
        const int n = n0 + r;
        const float dtv = dt_s[r];
        const float e = expf(lr * dtv);
        float sn, cs;
        sincosf(li * dtv, &sn, &cs);
        const float Ar = e * cs, Ai = e * sn;
        const float fr = ((Ar - 1.f) * lr + Ai * li) * linv;
        const float fi = (Ai * lr - (Ar - 1.f) * li) * linv;
        float cr = fr * bu_re[j] - fi * bu_im[j] + imr[j];
        float ci = fr * bu_im[j] + fi * bu_re[j] + imi[j];
        if (n == 0) {  // seed: c[0] += A[0]*x0
            cr += Ar * x0r[p] - Ai * x0i[p];
            ci += Ar * x0i[p] + Ai * x0r[p];
        }
        c_lds[r][p] = make_float2(cr, ci);
        ((float2*)c_ws)[((size_t)bi * Nn + n) * Pp + p] = make_float2(cr, ci);
    }
    __syncthreads();

    // phase 3: chunk-local scan (threads 0..127), aggregate out
    if (t < Pp) {
        float xr = 0.f, xi = 0.f, S = 0.f;
        for (int r = 0; r < Lc; ++r) {
            const float dtv = dt_s[r];
            S += dtv;
            const float e = expf(lr * dtv);
            float sn, cs;
            sincosf(li * dtv, &sn, &cs);
            const float Ar = e * cs, Ai = e * sn;
            const float2 cv = c_lds[r][t];
            const float nxr = fmaf(Ar, xr, fmaf(-Ai, xi, cv.x));
            const float nxi = fmaf(Ar, xi, fmaf(Ai, xr, cv.y));
            xr = nxr;
            xi = nxi;
        }
        ((float2*)xagg)[(size_t)bid * Pp + t] = make_float2(xr, xi);
        if (t == 0) Sdt[bid] = S;
    }
}

// ---------------- K2: inter-chunk scan, writes incoming state per chunk ----------------
__global__ void k2(const float* __restrict__ llnr, const float* __restrict__ lim,
                   const float* __restrict__ xagg, const float* __restrict__ Sdt,
                   float* __restrict__ x_in) {
    const int g = blockIdx.x * blockDim.x + threadIdx.x;  // 0..B*P-1
    const int bi = g / Pp, p = g % Pp;
    const float lr = -expf(llnr[p]);
    const float li = lim[p];
    float xr = 0.f, xi = 0.f;
    for (int ch = 0; ch < NCc; ++ch) {
        const size_t idx = ((size_t)bi * NCc + ch) * Pp + p;
        ((float2*)x_in)[idx] = make_float2(xr, xi);
        const float S = Sdt[bi * NCc + ch];
        const float e = expf(lr * S);
        float sn, cs;
        sincosf(li * S, &sn, &cs);
        const float Ar = e * cs, Ai = e * sn;
        const float2 ag = ((const float2*)xagg)[idx];
        const float nxr = fmaf(Ar, xr, fmaf(-Ai, xi, ag.x));
        const float nxi = fmaf(Ar, xi, fmaf(Ai, xr, ag.y));
        xr = nxr;
        xi = nxi;
    }
}

// ---------------- K3: replay scan per chunk + readout + LN/GELU/residual ----------------
__global__ __launch_bounds__(512) void k3(
    const float* __restrict__ left, const float* __restrict__ right,
    const float* __restrict__ mark, const float* __restrict__ dt,
    const float* __restrict__ llnr, const float* __restrict__ lim,
    const float* __restrict__ Dh_, const float* __restrict__ ln_g,
    const float* __restrict__ ln_b, const float* __restrict__ Ct2,
    const float* __restrict__ Mt, const float* __restrict__ c_ws,
    const float* __restrict__ x_in, float* __restrict__ out_l,
    float* __restrict__ out_r) {
    __shared__ float mark_t[Hh * LP];   // 36 KB, [h][r]
    __shared__ float2 x_t[Pp][LP];      // 36.9 KB, [p][r]
    __shared__ float dt_s[Lc];
    __shared__ float mu_l[Lc], rs_l[Lc], mu_r[Lc], rs_r[Lc];

    const int bid = blockIdx.x;
    const int bi = bid / NCc, ch = bid % NCc;
    const int n0 = ch * Lc;
    const int t = threadIdx.x;
    const int lane = t & 63, wave = t >> 6;

    if (t < Lc) dt_s[t] = dt[(size_t)bi * Nn + n0 + t];

    // stage mark transposed
#pragma unroll
    for (int k = 0; k < 16; ++k) {
        const int idx = k * 512 + t;
        const int r = idx >> 8, h = idx & 255;
        mark_t[h * LP + r] = mark[((size_t)bi * Nn + n0 + r) * Hh + h];
    }
    // LN stats for left (waves 0-3) and right (waves 4-7) rows
    {
        const int w = wave & 3;
        const float* src = (wave < 4) ? left : right;
        float* mus = (wave < 4) ? mu_l : mu_r;
        float* rss = (wave < 4) ? rs_l : rs_r;
        for (int rr = 0; rr < 8; ++rr) {
            const int r = w * 8 + rr;
            const float4 v = *reinterpret_cast<const float4*>(
                src + ((size_t)bi * Nn + n0 + r) * Hh + lane * 4);
            float s = v.x + v.y + v.z + v.w;
            float q = v.x * v.x + v.y * v.y + v.z * v.z + v.w * v.w;
#pragma unroll
            for (int off = 32; off; off >>= 1) {
                s += __shfl_xor(s, off);
                q += __shfl_xor(q, off);
            }
            if (lane == 0) {
                const float mu = s * (1.f / Hh);
                mus[r] = mu;
                rss[r] = rsqrtf(q * (1.f / Hh) - mu * mu + 1e-5f);
            }
        }
    }
    __syncthreads();

    // scan replay (threads 0..127)
    if (t < Pp) {
        const int p = t;
        const float lr = -expf(llnr[p]);
        const float li = lim[p];
        float2 cc[Lc];
        const float2* cws2 = (const float2*)c_ws;
#pragma unroll
        for (int r = 0; r < Lc; ++r)
            cc[r] = cws2[((size_t)bi * Nn + n0 + r) * Pp + p];
        const float2 x0v = ((const float2*)x_in)[(size_t)bid * Pp + p];
        float xr = x0v.x, xi = x0v.y;
        for (int r = 0; r < Lc; ++r) {
            const float dtv = dt_s[r];
            const float e = expf(lr * dtv);
            float sn, cs;
            sincosf(li * dtv, &sn, &cs);
            const float Ar = e * cs, Ai = e * sn;
            const float nxr = fmaf(Ar, xr, fmaf(-Ai, xi, cc[r].x));
            const float nxi = fmaf(Ar, xi, fmaf(Ai, xr, cc[r].y));
            xr = nxr;
            xi = nxi;
            x_t[p][r] = make_float2(xr, xi);
        }
    }
    __syncthreads();

    // readout: thread owns h = t&255, rows r0..r0+15
    const int h = t & 255;
    const int r0 = (t >> 8) * 16;
    float v[16] = {};
    float mt[16] = {};
    const float2* Ct = (const float2*)Ct2;
    for (int pp = 0; pp < Pp; ++pp) {
        const float2 Cv = Ct[pp * Hh + h];
#pragma unroll
        for (int j = 0; j < 16; ++j) {
            const float2 xv = x_t[pp][r0 + j];
            v[j] = fmaf(Cv.x, xv.x, fmaf(-Cv.y, xv.y, v[j]));
        }
    }
    for (int h2 = 0; h2 < Hh; ++h2) {
        const float Mv = Mt[h2 * Hh + h];
        const float* mp = &mark_t[h2 * LP + r0];
#pragma unroll
        for (int j = 0; j < 16; ++j) mt[j] = fmaf(Mv, mp[j], mt[j]);
    }
    const float Dv = Dh_[h], gv = ln_g[h], bv = ln_b[h];
#pragma unroll
    for (int j = 0; j < 16; ++j) {
        const int r = r0 + j;
        const size_t off = ((size_t)bi * Nn + n0 + r) * Hh + h;
        const float lraw = left[off], rraw = right[off];
        const float ul = (lraw - mu_l[r]) * rs_l[r] * gv + bv;
        const float ur = (rraw - mu_r[r]) * rs_r[r] * gv + bv;
        const float yl = 2.f * v[j] - mt[j] + Dv * ul;
        const float yr = 2.f * v[j] + Dv * ur;
        out_l[off] = gelu_f(yl) + lraw;
        out_r[off] = gelu_f(yr) + rraw;
    }
}

extern "C" void kernel_launch(void* const* d_in, const int* in_sizes, int n_in,
                              void* d_out, int out_size, void* d_ws, size_t ws_size,
                              hipStream_t stream) {
    const float* left = (const float*)d_in[0];
    const float* right = (const float*)d_in[1];
    const float* mark = (const float*)d_in[2];
    const float* dt = (const float*)d_in[3];
    const float* llnr = (const float*)d_in[4];
    const float* lim = (const float*)d_in[5];
    const float* B_re = (const float*)d_in[6];
    const float* B_im = (const float*)d_in[7];
    const float* C_re = (const float*)d_in[8];
    const float* C_im = (const float*)d_in[9];
    const float* E_re = (const float*)d_in[10];
    const float* E_im = (const float*)d_in[11];
    const float* D_H = (const float*)d_in[12];
    const float* x0r = (const float*)d_in[13];
    const float* x0i = (const float*)d_in[14];
    const float* ln_g = (const float*)d_in[15];
    const float* ln_b = (const float*)d_in[16];

    float* ws = (float*)d_ws;
    float* Bt2 = ws;                                    // 2*H*P
    float* Et2 = Bt2 + 2 * Hh * Pp;                     // 2*H*P
    float* Ct2 = Et2 + 2 * Hh * Pp;                     // 2*H*P
    float* Mt = Ct2 + 2 * Hh * Pp;                      // H*H
    float* c_ws = Mt + Hh * Hh;                         // 2*B*N*P
    float* xagg = c_ws + (size_t)2 * Bb * Nn * Pp;      // 2*B*NC*P
    float* x_in = xagg + (size_t)2 * Bb * NCc * Pp;     // 2*B*NC*P
    float* Sdt = x_in + (size_t)2 * Bb * NCc * Pp;      // B*NC
    const size_t need = (size_t)(Sdt - ws) + Bb * NCc;
    if (ws_size < need * sizeof(float)) return;  // fail loudly (validation will catch)

    float* out_l = (float*)d_out;
    float* out_r = out_l + (size_t)Bb * Nn * Hh;

    hipLaunchKernelGGL(k0_transpose, dim3(128), dim3(256), 0, stream,
                       B_re, B_im, E_re, E_im, C_re, C_im, Bt2, Et2, Ct2);
    hipLaunchKernelGGL(k0_M, dim3(256), dim3(256), 0, stream, C_re, C_im, E_re, E_im, Mt);
    hipLaunchKernelGGL(k1, dim3(Bb * NCc), dim3(512), 0, stream, right, mark, dt, llnr,
                       lim, x0r, x0i, ln_g, ln_b, Bt2, Et2, c_ws, xagg, Sdt);
    hipLaunchKernelGGL(k2, dim3((Bb * Pp) / 256), dim3(256), 0, stream, llnr, lim, xagg,
                       Sdt, x_in);
    hipLaunchKernelGGL(k3, dim3(Bb * NCc), dim3(512), 0, stream, left, right, mark, dt,
                       llnr, lim, D_H, ln_g, ln_b, Ct2, Mt, c_ws, x_in, out_l, out_r);
}